// Round 3
// baseline (642.085 us; speedup 1.0000x reference)
//
#include <hip/hip_runtime.h>
#include <hip/hip_bf16.h>

// HCNet: L=4 hyper-connection blocks, N=4, D=2048, B*T=4096 tokens.
// R3: width/depth kernels are latency-bound (VALU 31%, occ 10.8%) -> split each
// token across 2 waves + LDS combine; precompute token-independent S0/T0 sums;
// pack W_r/W_b to bf16. Wt lives in d_out (recomputed each call).

#define DD 2048
#define NN 4
#define LL 4
#define NTOK 4096
#define EPSF 1e-5f

typedef __attribute__((ext_vector_type(8))) short bf16x8;
typedef __attribute__((ext_vector_type(4))) float f32x4;

__device__ __forceinline__ float bf2f(short u) {
  union { unsigned int i; float f; } v;
  v.i = ((unsigned int)(unsigned short)u) << 16;
  return v.f;
}
__device__ __forceinline__ short f2bf(float f) {
  union { float f; unsigned int i; } v; v.f = f;
  unsigned int x = v.i;
  return (short)((x + 0x7fffu + ((x >> 16) & 1u)) >> 16);  // RNE
}
__device__ __forceinline__ float wred(float v) {
#pragma unroll
  for (int off = 32; off > 0; off >>= 1) v += __shfl_xor(v, off, 64);
  return v;
}
__device__ __forceinline__ void ld16(const void* g, void* l) {
  __builtin_amdgcn_global_load_lds(
      (const __attribute__((address_space(1))) void*)g,
      (__attribute__((address_space(3))) void*)l, 16, 0, 0);
}

// ---------------- pack W_r / W_b to bf16 ------------------------------------
__global__ __launch_bounds__(256) void prep_pack(
    const float* __restrict__ W_r, const float* __restrict__ W_b,
    short* __restrict__ wrb, short* __restrict__ wbb) {
  const int i = blockIdx.x * 256 + threadIdx.x;  // over L*D = 8192
  f32x4 r = *(const f32x4*)(W_r + (size_t)i * 4);
  f32x4 b = *(const f32x4*)(W_b + (size_t)i * 4);
  short ro[4], bo[4];
#pragma unroll
  for (int k = 0; k < 4; k++) { ro[k] = f2bf(r[k]); bo[k] = f2bf(b[k]); }
  *(unsigned long long*)(wrb + (size_t)i * 4) = *(unsigned long long*)ro;
  *(unsigned long long*)(wbb + (size_t)i * 4) = *(unsigned long long*)bo;
}

// ---------------- token-independent sums S0w[l][5], T0d[l][4] ---------------
__global__ __launch_bounds__(64) void prep_sums(
    const float* __restrict__ W_m, const float* __restrict__ W_r,
    const float* __restrict__ W_b, const float* __restrict__ dyn_gamma,
    float* __restrict__ S0w, float* __restrict__ T0d) {
  const int l = blockIdx.x;
  const int lane = threadIdx.x;
  float s[5] = {0, 0, 0, 0, 0}, t[4] = {0, 0, 0, 0};
  for (int d = lane; d < DD; d += 64) {
    const float g = dyn_gamma[l * DD + d];
    s[0] += g * W_m[l * DD + d];
    f32x4 r = *(const f32x4*)(W_r + ((size_t)l * DD + d) * 4);
    f32x4 b = *(const f32x4*)(W_b + ((size_t)l * DD + d) * 4);
#pragma unroll
    for (int m = 0; m < 4; m++) { s[1 + m] += g * r[m]; t[m] += g * b[m]; }
  }
#pragma unroll
  for (int m = 0; m < 5; m++) s[m] = wred(s[m]);
#pragma unroll
  for (int n = 0; n < 4; n++) t[n] = wred(t[n]);
  if (lane == 0) {
#pragma unroll
    for (int m = 0; m < 5; m++) S0w[l * 5 + m] = s[m];
#pragma unroll
    for (int n = 0; n < 4; n++) T0d[l * 4 + n] = t[n];
  }
}

// ---------------- transpose Wblk[l][d][e] (f32) -> Wt[l][e][d] (bf16) -------
__global__ __launch_bounds__(256) void transpose_wblk(
    const float* __restrict__ W, short* __restrict__ Wt) {
  __shared__ float tile[64][65];
  const int blk = blockIdx.z;
  const int c0 = blockIdx.x * 64;
  const int r0 = blockIdx.y * 64;
  const float* Ws = W + (size_t)blk * DD * DD;
  short* Wd = Wt + (size_t)blk * DD * DD;
  const int tx = threadIdx.x & 63, ty = threadIdx.x >> 6;
#pragma unroll
  for (int r = 0; r < 16; r++) {
    const int row = ty + r * 4;
    tile[row][tx] = Ws[(size_t)(r0 + row) * DD + c0 + tx];
  }
  __syncthreads();
#pragma unroll
  for (int r = 0; r < 16; r++) {
    const int row = ty + r * 4;
    Wd[(size_t)(c0 + row) * DD + r0 + tx] = f2bf(tile[tx][row]);
  }
}

// ---------------- width connections, block 0 (reads x f32) ------------------
// 2 waves per token (D-halves), 2 tokens per 256-thread block.
__global__ __launch_bounds__(256, 4) void width0_kernel(
    const float* __restrict__ x, short* __restrict__ Hst,
    short* __restrict__ hnorm, const float* __restrict__ A_m,
    const float* __restrict__ A_r, const float* __restrict__ W_m,
    const short* __restrict__ wrb, const float* __restrict__ s_a,
    const float* __restrict__ dyn_gamma, const float* __restrict__ norm_gamma,
    const float* __restrict__ norm_beta, const float* __restrict__ S0w) {
  __shared__ float redA[2][2][7];
  __shared__ float redC[2][2][2];
  const int tid = threadIdx.x;
  const int lane = tid & 63;
  const int wave = tid >> 6;
  const int ti = wave >> 1;   // token in block
  const int wh = wave & 1;    // D-half
  const int tok = blockIdx.x * 2 + ti;
  const int blk = 0;
  const float* dg = dyn_gamma + blk * DD;
  const float* wm = W_m + blk * DD;
  const short* wr = wrb + (size_t)blk * DD * 4;
  const int dbase = wh * 1024 + lane * 8;

  bf16x8 hreg[2];  // all N rows identical at block 0
  const float* xr = x + (size_t)tok * DD;
#pragma unroll
  for (int jj = 0; jj < 2; jj++) {
    const int d0 = dbase + jj * 512;
    f32x4 a = *(const f32x4*)(xr + d0);
    f32x4 b = *(const f32x4*)(xr + d0 + 4);
    bf16x8 p;
#pragma unroll
    for (int q = 0; q < 4; q++) { p[q] = f2bf(a[q]); p[4 + q] = f2bf(b[q]); }
    hreg[jj] = p;
  }

  float sH = 0, sH2 = 0, S1[5] = {0, 0, 0, 0, 0};
#pragma unroll
  for (int jj = 0; jj < 2; jj++) {
    const int d0 = dbase + jj * 512;
    f32x4 g0 = *(const f32x4*)(dg + d0), g1 = *(const f32x4*)(dg + d0 + 4);
    f32x4 m0 = *(const f32x4*)(wm + d0), m1 = *(const f32x4*)(wm + d0 + 4);
    bf16x8 wv[4];
#pragma unroll
    for (int p = 0; p < 4; p++)
      wv[p] = *(const bf16x8*)(wr + (size_t)(d0 + 2 * p) * 4);
#pragma unroll
    for (int q = 0; q < 8; q++) {
      const float g = (q < 4) ? g0[q] : g1[q - 4];
      const float wmv = (q < 4) ? m0[q] : m1[q - 4];
      const float hv = bf2f(hreg[jj][q]);
      sH += hv; sH2 += hv * hv;
      const float hg = hv * g;
      S1[0] += hg * wmv;
#pragma unroll
      for (int m = 0; m < 4; m++)
        S1[1 + m] += hg * bf2f(wv[q >> 1][(q & 1) * 4 + m]);
    }
  }
  sH = wred(sH); sH2 = wred(sH2);
#pragma unroll
  for (int m = 0; m < 5; m++) S1[m] = wred(S1[m]);
  if (lane == 0) {
    float* p = &redA[ti][wh][0];
    p[0] = sH; p[1] = sH2;
#pragma unroll
    for (int m = 0; m < 5; m++) p[2 + m] = S1[m];
  }
  __syncthreads();
  const float sHt = redA[ti][0][0] + redA[ti][1][0];
  const float sH2t = redA[ti][0][1] + redA[ti][1][1];
  float S1t[5];
#pragma unroll
  for (int m = 0; m < 5; m++) S1t[m] = redA[ti][0][2 + m] + redA[ti][1][2 + m];

  const float sa = s_a[blk];
  const float mu0 = sHt * (1.f / DD);
  const float inv0 = rsqrtf(sH2t * (1.f / DD) - mu0 * mu0 + EPSF);
  // N rows identical -> only column sums matter for apply
  float amSum = 0.f, arCol[NN] = {0, 0, 0, 0};
  {
    const float t0 = tanhf(inv0 * (S1t[0] - mu0 * S0w[blk * 5 + 0]));
    float tm[NN];
#pragma unroll
    for (int m = 0; m < NN; m++)
      tm[m] = tanhf(inv0 * (S1t[1 + m] - mu0 * S0w[blk * 5 + 1 + m]));
#pragma unroll
    for (int n = 0; n < NN; n++) {
      amSum += A_m[blk * NN + n] + sa * t0;
#pragma unroll
      for (int m = 0; m < NN; m++)
        arCol[m] += A_r[blk * NN * NN + n * NN + m] + sa * tm[m];
    }
  }

  short* Ho = Hst + (size_t)tok * NN * DD;
  float hbuf[2][8];
  float sh = 0.f, sh2 = 0.f;
#pragma unroll
  for (int jj = 0; jj < 2; jj++) {
    const int d0 = dbase + jj * 512;
    bf16x8 outp[NN];
#pragma unroll
    for (int q = 0; q < 8; q++) {
      const float hv = bf2f(hreg[jj][q]);
      const float a0 = hv * amSum;
      hbuf[jj][q] = a0; sh += a0; sh2 += a0 * a0;
#pragma unroll
      for (int m = 0; m < NN; m++) outp[m][q] = f2bf(hv * arCol[m]);
    }
#pragma unroll
    for (int m = 0; m < NN; m++) *(bf16x8*)(Ho + m * DD + d0) = outp[m];
  }
  sh = wred(sh); sh2 = wred(sh2);
  if (lane == 0) { redC[ti][wh][0] = sh; redC[ti][wh][1] = sh2; }
  __syncthreads();
  const float sht = redC[ti][0][0] + redC[ti][1][0];
  const float sh2t = redC[ti][0][1] + redC[ti][1][1];
  const float mu = sht * (1.f / DD);
  const float inv = rsqrtf(sh2t * (1.f / DD) - mu * mu + EPSF);
  const float* ng = norm_gamma + blk * DD;
  const float* nb = norm_beta + blk * DD;
  short* hn = hnorm + (size_t)tok * DD;
#pragma unroll
  for (int jj = 0; jj < 2; jj++) {
    const int d0 = dbase + jj * 512;
    f32x4 g0 = *(const f32x4*)(ng + d0), g1 = *(const f32x4*)(ng + d0 + 4);
    f32x4 b0 = *(const f32x4*)(nb + d0), b1 = *(const f32x4*)(nb + d0 + 4);
    bf16x8 o;
#pragma unroll
    for (int q = 0; q < 8; q++) {
      const float g = (q < 4) ? g0[q] : g1[q - 4];
      const float b = (q < 4) ? b0[q] : b1[q - 4];
      o[q] = f2bf((hbuf[jj][q] - mu) * inv * g + b);
    }
    *(bf16x8*)(hn + d0) = o;
  }
}

// ---------------- block GEMM: h2 = hnorm @ Wblk^T + bias --------------------
__global__ __launch_bounds__(256) void gemm_kernel(
    const short* __restrict__ A, const short* __restrict__ Bt,
    const float* __restrict__ bias, short* __restrict__ C) {
  __shared__ short lA[2][128 * 64];
  __shared__ short lB[2][128 * 64];
  const int tid = threadIdx.x;
  const int lane = tid & 63;
  const int wave = tid >> 6;
  const int m0 = blockIdx.x * 128, n0 = blockIdx.y * 128;
  const int wm = wave >> 1, wn = wave & 1;

  f32x4 acc[4][4] = {};

#define STAGE(buf, kt)                                                        \
  {                                                                           \
    const int k0 = (kt) * 64;                                                 \
    _Pragma("unroll") for (int c = 0; c < 4; c++) {                           \
      const int idx = c * 256 + tid;                                          \
      const int row = idx >> 3;                                               \
      const int colsw = (((idx & 7) ^ (row & 7)) * 8);                        \
      ld16(A + (size_t)(m0 + row) * DD + k0 + colsw,                          \
           (char*)&lA[buf][0] + idx * 16);                                    \
      ld16(Bt + (size_t)(n0 + row) * DD + k0 + colsw,                         \
           (char*)&lB[buf][0] + idx * 16);                                    \
    }                                                                         \
  }

  STAGE(0, 0);
  __syncthreads();

  for (int kt = 0; kt < 32; ++kt) {
    const int cur = kt & 1;
    if (kt < 31) STAGE(cur ^ 1, kt + 1);
    const char* bufA = (const char*)&lA[cur][0];
    const char* bufB = (const char*)&lB[cur][0];
#pragma unroll
    for (int kk = 0; kk < 2; ++kk) {
      const int gsw = (kk * 64 + (lane >> 4) * 16) ^ ((lane & 7) << 4);
      bf16x8 af[4], bfr[4];
#pragma unroll
      for (int m = 0; m < 4; m++) {
        const int r = wm * 64 + m * 16 + (lane & 15);
        af[m] = *(const bf16x8*)(bufA + r * 128 + gsw);
      }
#pragma unroll
      for (int n = 0; n < 4; n++) {
        const int r = wn * 64 + n * 16 + (lane & 15);
        bfr[n] = *(const bf16x8*)(bufB + r * 128 + gsw);
      }
#pragma unroll
      for (int m = 0; m < 4; m++)
#pragma unroll
        for (int n = 0; n < 4; n++)
          acc[m][n] = __builtin_amdgcn_mfma_f32_16x16x32_bf16(
              af[m], bfr[n], acc[m][n], 0, 0, 0);
    }
    __syncthreads();
  }
#undef STAGE

#pragma unroll
  for (int n = 0; n < 4; n++) {
    const int col = n0 + wn * 64 + n * 16 + (lane & 15);
    const float bv = bias[col];
#pragma unroll
    for (int m = 0; m < 4; m++) {
      const int rbase = m0 + wm * 64 + m * 16 + ((lane >> 4) << 2);
#pragma unroll
      for (int j = 0; j < 4; j++)
        C[(size_t)(rbase + j) * DD + col] = f2bf(acc[m][n][j] + bv);
    }
  }
}

// ---------------- fused depth(blk) + width(blk+1), 2 waves per token --------
__global__ __launch_bounds__(256, 4) void fused_dw(
    const short* __restrict__ h2, short* __restrict__ Hst,
    short* __restrict__ hnorm, const float* __restrict__ Bp,
    const short* __restrict__ wbb, const float* __restrict__ s_b,
    const float* __restrict__ A_m, const float* __restrict__ A_r,
    const float* __restrict__ W_m, const short* __restrict__ wrb,
    const float* __restrict__ s_a, const float* __restrict__ dyn_gamma,
    const float* __restrict__ norm_gamma, const float* __restrict__ norm_beta,
    const float* __restrict__ S0w, const float* __restrict__ T0d, int blk) {
  __shared__ float redA[2][2][6];
  __shared__ float redB[2][2][28];
  __shared__ float redC[2][2][2];
  const int tid = threadIdx.x;
  const int lane = tid & 63;
  const int wave = tid >> 6;
  const int ti = wave >> 1;
  const int wh = wave & 1;
  const int tok = blockIdx.x * 2 + ti;
  const int nblk = blk + 1;
  const short* hr = h2 + (size_t)tok * DD;
  short* Ho = Hst + (size_t)tok * NN * DD;
  const int dbase = wh * 1024 + lane * 8;

  // ---- issue big loads early ----
  bf16x8 h2r[2], hold[NN][2];
#pragma unroll
  for (int jj = 0; jj < 2; jj++) {
    const int d0 = dbase + jj * 512;
    h2r[jj] = *(const bf16x8*)(hr + d0);
#pragma unroll
    for (int n = 0; n < NN; n++)
      hold[n][jj] = *(const bf16x8*)(Ho + n * DD + d0);
  }

  // ---- depth stats on h2 ----
  const float* dgd = dyn_gamma + blk * DD;
  const short* wb = wbb + (size_t)blk * DD * 4;
  float s1 = 0.f, s2 = 0.f, T1[NN] = {0, 0, 0, 0};
#pragma unroll
  for (int jj = 0; jj < 2; jj++) {
    const int d0 = dbase + jj * 512;
    f32x4 g0 = *(const f32x4*)(dgd + d0), g1 = *(const f32x4*)(dgd + d0 + 4);
    bf16x8 wv[4];
#pragma unroll
    for (int p = 0; p < 4; p++)
      wv[p] = *(const bf16x8*)(wb + (size_t)(d0 + 2 * p) * 4);
#pragma unroll
    for (int q = 0; q < 8; q++) {
      const float g = (q < 4) ? g0[q] : g1[q - 4];
      const float hv = bf2f(h2r[jj][q]);
      s1 += hv; s2 += hv * hv;
      const float hg = hv * g;
#pragma unroll
      for (int n = 0; n < NN; n++)
        T1[n] += hg * bf2f(wv[q >> 1][(q & 1) * 4 + n]);
    }
  }
  s1 = wred(s1); s2 = wred(s2);
#pragma unroll
  for (int n = 0; n < NN; n++) T1[n] = wred(T1[n]);
  if (lane == 0) {
    float* p = &redA[ti][wh][0];
    p[0] = s1; p[1] = s2;
#pragma unroll
    for (int n = 0; n < NN; n++) p[2 + n] = T1[n];
  }
  __syncthreads();
  float Bv[NN];
  {
    const float s1t = redA[ti][0][0] + redA[ti][1][0];
    const float s2t = redA[ti][0][1] + redA[ti][1][1];
    const float mu = s1t * (1.f / DD);
    const float inv = rsqrtf(s2t * (1.f / DD) - mu * mu + EPSF);
    const float sb = s_b[blk];
#pragma unroll
    for (int n = 0; n < NN; n++) {
      const float t1t = redA[ti][0][2 + n] + redA[ti][1][2 + n];
      Bv[n] = Bp[blk * NN + n] +
              sb * tanhf(inv * (t1t - mu * T0d[blk * NN + n]));
    }
  }
  // ---- H' = H + h2 * Bv ----
#pragma unroll
  for (int n = 0; n < NN; n++)
#pragma unroll
    for (int jj = 0; jj < 2; jj++) {
      bf16x8 o;
#pragma unroll
      for (int q = 0; q < 8; q++)
        o[q] = f2bf(bf2f(hold[n][jj][q]) + bf2f(h2r[jj][q]) * Bv[n]);
      hold[n][jj] = o;
    }

  // ---- width stats of block nblk on H' ----
  const float* dg = dyn_gamma + nblk * DD;
  const float* wm = W_m + nblk * DD;
  const short* wr = wrb + (size_t)nblk * DD * 4;
  float sH[NN] = {0, 0, 0, 0}, sH2[NN] = {0, 0, 0, 0};
  float S1[NN][5];
#pragma unroll
  for (int n = 0; n < NN; n++)
#pragma unroll
    for (int m = 0; m < 5; m++) S1[n][m] = 0.f;

#pragma unroll
  for (int jj = 0; jj < 2; jj++) {
    const int d0 = dbase + jj * 512;
    f32x4 g0 = *(const f32x4*)(dg + d0), g1 = *(const f32x4*)(dg + d0 + 4);
    f32x4 m0 = *(const f32x4*)(wm + d0), m1 = *(const f32x4*)(wm + d0 + 4);
    bf16x8 wv[4];
#pragma unroll
    for (int p = 0; p < 4; p++)
      wv[p] = *(const bf16x8*)(wr + (size_t)(d0 + 2 * p) * 4);
#pragma unroll
    for (int q = 0; q < 8; q++) {
      const float g = (q < 4) ? g0[q] : g1[q - 4];
      const float wmv = (q < 4) ? m0[q] : m1[q - 4];
      float gw[5];
      gw[0] = g * wmv;
#pragma unroll
      for (int m = 0; m < 4; m++)
        gw[1 + m] = g * bf2f(wv[q >> 1][(q & 1) * 4 + m]);
#pragma unroll
      for (int n = 0; n < NN; n++) {
        const float hv = bf2f(hold[n][jj][q]);
        sH[n] += hv; sH2[n] += hv * hv;
#pragma unroll
        for (int m = 0; m < 5; m++) S1[n][m] += hv * gw[m];
      }
    }
  }
#pragma unroll
  for (int n = 0; n < NN; n++) { sH[n] = wred(sH[n]); sH2[n] = wred(sH2[n]); }
#pragma unroll
  for (int n = 0; n < NN; n++)
#pragma unroll
    for (int m = 0; m < 5; m++) S1[n][m] = wred(S1[n][m]);
  if (lane == 0) {
    float* p = &redB[ti][wh][0];
#pragma unroll
    for (int n = 0; n < NN; n++) { p[n] = sH[n]; p[4 + n] = sH2[n]; }
#pragma unroll
    for (int n = 0; n < NN; n++)
#pragma unroll
      for (int m = 0; m < 5; m++) p[8 + n * 5 + m] = S1[n][m];
  }
  __syncthreads();

  const float sa = s_a[nblk];
  float Am[NN], Ar[NN][NN];
#pragma unroll
  for (int n = 0; n < NN; n++) {
    const float sHt = redB[ti][0][n] + redB[ti][1][n];
    const float sH2t = redB[ti][0][4 + n] + redB[ti][1][4 + n];
    const float mu = sHt * (1.f / DD);
    const float inv = rsqrtf(sH2t * (1.f / DD) - mu * mu + EPSF);
    const float s10 = redB[ti][0][8 + n * 5] + redB[ti][1][8 + n * 5];
    Am[n] = A_m[nblk * NN + n] +
            sa * tanhf(inv * (s10 - mu * S0w[nblk * 5 + 0]));
#pragma unroll
    for (int m = 0; m < NN; m++) {
      const float s1m =
          redB[ti][0][8 + n * 5 + 1 + m] + redB[ti][1][8 + n * 5 + 1 + m];
      Ar[n][m] = A_r[nblk * NN * NN + n * NN + m] +
                 sa * tanhf(inv * (s1m - mu * S0w[nblk * 5 + 1 + m]));
    }
  }

  float hbuf[2][8];
  float sh = 0.f, sh2 = 0.f;
#pragma unroll
  for (int jj = 0; jj < 2; jj++) {
    const int d0 = dbase + jj * 512;
    bf16x8 outp[NN];
#pragma unroll
    for (int q = 0; q < 8; q++) {
      float a0 = 0.f, am0 = 0.f, am1 = 0.f, am2 = 0.f, am3 = 0.f;
#pragma unroll
      for (int n = 0; n < NN; n++) {
        const float hv = bf2f(hold[n][jj][q]);
        a0 += hv * Am[n];
        am0 += hv * Ar[n][0];
        am1 += hv * Ar[n][1];
        am2 += hv * Ar[n][2];
        am3 += hv * Ar[n][3];
      }
      hbuf[jj][q] = a0; sh += a0; sh2 += a0 * a0;
      outp[0][q] = f2bf(am0); outp[1][q] = f2bf(am1);
      outp[2][q] = f2bf(am2); outp[3][q] = f2bf(am3);
    }
#pragma unroll
    for (int m = 0; m < NN; m++) *(bf16x8*)(Ho + m * DD + d0) = outp[m];
  }
  sh = wred(sh); sh2 = wred(sh2);
  if (lane == 0) { redC[ti][wh][0] = sh; redC[ti][wh][1] = sh2; }
  __syncthreads();
  const float sht = redC[ti][0][0] + redC[ti][1][0];
  const float sh2t = redC[ti][0][1] + redC[ti][1][1];
  const float mu = sht * (1.f / DD);
  const float inv = rsqrtf(sh2t * (1.f / DD) - mu * mu + EPSF);
  const float* ng = norm_gamma + nblk * DD;
  const float* nb = norm_beta + nblk * DD;
  short* hn = hnorm + (size_t)tok * DD;
#pragma unroll
  for (int jj = 0; jj < 2; jj++) {
    const int d0 = dbase + jj * 512;
    f32x4 g0 = *(const f32x4*)(ng + d0), g1 = *(const f32x4*)(ng + d0 + 4);
    f32x4 b0 = *(const f32x4*)(nb + d0), b1 = *(const f32x4*)(nb + d0 + 4);
    bf16x8 o;
#pragma unroll
    for (int q = 0; q < 8; q++) {
      const float g = (q < 4) ? g0[q] : g1[q - 4];
      const float b = (q < 4) ? b0[q] : b1[q - 4];
      o[q] = f2bf((hbuf[jj][q] - mu) * inv * g + b);
    }
    *(bf16x8*)(hn + d0) = o;
  }
}

// ---------------- final depth (block 3) + output sum ------------------------
__global__ __launch_bounds__(256, 4) void depth_last(
    const short* __restrict__ h2, const short* __restrict__ Hst,
    float* __restrict__ out, const float* __restrict__ Bp,
    const short* __restrict__ wbb, const float* __restrict__ s_b,
    const float* __restrict__ dyn_gamma, const float* __restrict__ T0d,
    int blk) {
  __shared__ float redA[2][2][6];
  const int tid = threadIdx.x;
  const int lane = tid & 63;
  const int wave = tid >> 6;
  const int ti = wave >> 1;
  const int wh = wave & 1;
  const int tok = blockIdx.x * 2 + ti;
  const short* hr = h2 + (size_t)tok * DD;
  const float* dg = dyn_gamma + blk * DD;
  const short* wb = wbb + (size_t)blk * DD * 4;
  const int dbase = wh * 1024 + lane * 8;

  bf16x8 h2r[2];
  float s1 = 0.f, s2 = 0.f, T1[NN] = {0, 0, 0, 0};
#pragma unroll
  for (int jj = 0; jj < 2; jj++) {
    const int d0 = dbase + jj * 512;
    h2r[jj] = *(const bf16x8*)(hr + d0);
    f32x4 g0 = *(const f32x4*)(dg + d0), g1 = *(const f32x4*)(dg + d0 + 4);
    bf16x8 wv[4];
#pragma unroll
    for (int p = 0; p < 4; p++)
      wv[p] = *(const bf16x8*)(wb + (size_t)(d0 + 2 * p) * 4);
#pragma unroll
    for (int q = 0; q < 8; q++) {
      const float g = (q < 4) ? g0[q] : g1[q - 4];
      const float hv = bf2f(h2r[jj][q]);
      s1 += hv; s2 += hv * hv;
      const float hg = hv * g;
#pragma unroll
      for (int n = 0; n < NN; n++)
        T1[n] += hg * bf2f(wv[q >> 1][(q & 1) * 4 + n]);
    }
  }
  s1 = wred(s1); s2 = wred(s2);
#pragma unroll
  for (int n = 0; n < NN; n++) T1[n] = wred(T1[n]);
  if (lane == 0) {
    float* p = &redA[ti][wh][0];
    p[0] = s1; p[1] = s2;
#pragma unroll
    for (int n = 0; n < NN; n++) p[2 + n] = T1[n];
  }
  __syncthreads();
  const float s1t = redA[ti][0][0] + redA[ti][1][0];
  const float s2t = redA[ti][0][1] + redA[ti][1][1];
  const float mu = s1t * (1.f / DD);
  const float inv = rsqrtf(s2t * (1.f / DD) - mu * mu + EPSF);
  const float sb = s_b[blk];
  float bsum = 0.f;
#pragma unroll
  for (int n = 0; n < NN; n++) {
    const float t1t = redA[ti][0][2 + n] + redA[ti][1][2 + n];
    bsum += Bp[blk * NN + n] + sb * tanhf(inv * (t1t - mu * T0d[blk * NN + n]));
  }

  const short* Ho = Hst + (size_t)tok * NN * DD;
  float* orow = out + (size_t)tok * DD;
#pragma unroll
  for (int jj = 0; jj < 2; jj++) {
    const int d0 = dbase + jj * 512;
    bf16x8 hrow[NN];
#pragma unroll
    for (int n = 0; n < NN; n++) hrow[n] = *(const bf16x8*)(Ho + n * DD + d0);
    f32x4 o0, o1;
#pragma unroll
    for (int q = 0; q < 8; q++) {
      const float hv = bf2f(h2r[jj][q]);
      float s = hv * bsum;
#pragma unroll
      for (int n = 0; n < NN; n++) s += bf2f(hrow[n][q]);
      if (q < 4) o0[q] = s; else o1[q - 4] = s;
    }
    *(f32x4*)(orow + d0) = o0;
    *(f32x4*)(orow + d0 + 4) = o1;
  }
}

extern "C" void kernel_launch(void* const* d_in, const int* in_sizes, int n_in,
                              void* d_out, int out_size, void* d_ws,
                              size_t ws_size, hipStream_t stream) {
  const float* x = (const float*)d_in[0];
  const float* A_m = (const float*)d_in[1];
  const float* A_r = (const float*)d_in[2];
  const float* Bp = (const float*)d_in[3];
  const float* W_m = (const float*)d_in[4];
  const float* W_r = (const float*)d_in[5];
  const float* W_b = (const float*)d_in[6];
  const float* s_a = (const float*)d_in[7];
  const float* s_b = (const float*)d_in[8];
  const float* dyn_gamma = (const float*)d_in[9];
  const float* norm_gamma = (const float*)d_in[10];
  const float* norm_beta = (const float*)d_in[11];
  const float* Wblk = (const float*)d_in[12];
  const float* bblk = (const float*)d_in[13];
  float* out = (float*)d_out;

  char* ws = (char*)d_ws;
  short* Hst = (short*)(ws);                        // 64 MiB
  short* hnorm = (short*)(ws + 67108864);           // 16 MiB
  short* h2 = (short*)(ws + 83886080);              // 16 MiB
  short* wrb = (short*)(ws + 100663296);            // 64 KiB
  short* wbb = (short*)(ws + 100663296 + 65536);    // 64 KiB
  float* S0w = (float*)(ws + 100663296 + 131072);   // 80 B
  float* T0d = (float*)(ws + 100663296 + 131072 + 128);
  // Wt lives in d_out: recomputed every call, overwritten by depth_last at end
  short* Wt = (short*)d_out;

  dim3 tb(256);
  prep_pack<<<32, tb, 0, stream>>>(W_r, W_b, wrb, wbb);
  prep_sums<<<4, dim3(64), 0, stream>>>(W_m, W_r, W_b, dyn_gamma, S0w, T0d);
  transpose_wblk<<<dim3(32, 32, 4), tb, 0, stream>>>(Wblk, Wt);
  width0_kernel<<<2048, tb, 0, stream>>>(x, Hst, hnorm, A_m, A_r, W_m, wrb,
                                         s_a, dyn_gamma, norm_gamma, norm_beta,
                                         S0w);
  for (int i = 0; i < LL; i++) {
    gemm_kernel<<<dim3(32, 16), tb, 0, stream>>>(
        hnorm, Wt + (size_t)i * DD * DD, bblk + i * DD, h2);
    if (i < LL - 1)
      fused_dw<<<2048, tb, 0, stream>>>(h2, Hst, hnorm, Bp, wbb, s_b, A_m, A_r,
                                        W_m, wrb, s_a, dyn_gamma, norm_gamma,
                                        norm_beta, S0w, T0d, i);
    else
      depth_last<<<2048, tb, 0, stream>>>(h2, Hst, out, Bp, wbb, s_b,
                                          dyn_gamma, T0d, i);
  }
}

// Round 4
// 392.004 us; speedup vs baseline: 1.6380x; 1.6380x over previous
//
#include <hip/hip_runtime.h>
#include <hip/hip_bf16.h>

// HCNet: L=4 hyper-connection blocks, N=4, D=2048, B*T=4096 tokens.
// R4: revert to R2's 1-wave-per-token structure (R3's 2-wave split caused
// 4x HBM write amplification); keep validated wins: S0w/T0d precompute,
// bf16-packed W_r/W_b, width0 col-sum trick. Wt lives in d_out.

#define DD 2048
#define NN 4
#define LL 4
#define NTOK 4096
#define EPSF 1e-5f

typedef __attribute__((ext_vector_type(8))) short bf16x8;
typedef __attribute__((ext_vector_type(4))) float f32x4;

__device__ __forceinline__ float bf2f(short u) {
  union { unsigned int i; float f; } v;
  v.i = ((unsigned int)(unsigned short)u) << 16;
  return v.f;
}
__device__ __forceinline__ short f2bf(float f) {
  union { float f; unsigned int i; } v; v.f = f;
  unsigned int x = v.i;
  return (short)((x + 0x7fffu + ((x >> 16) & 1u)) >> 16);  // RNE
}
__device__ __forceinline__ float wred(float v) {
#pragma unroll
  for (int off = 32; off > 0; off >>= 1) v += __shfl_xor(v, off, 64);
  return v;
}
__device__ __forceinline__ void ld16(const void* g, void* l) {
  __builtin_amdgcn_global_load_lds(
      (const __attribute__((address_space(1))) void*)g,
      (__attribute__((address_space(3))) void*)l, 16, 0, 0);
}

// ---------------- pack W_r / W_b to bf16 ------------------------------------
__global__ __launch_bounds__(256) void prep_pack(
    const float* __restrict__ W_r, const float* __restrict__ W_b,
    short* __restrict__ wrb, short* __restrict__ wbb) {
  const int i = blockIdx.x * 256 + threadIdx.x;  // over L*D = 8192
  f32x4 r = *(const f32x4*)(W_r + (size_t)i * 4);
  f32x4 b = *(const f32x4*)(W_b + (size_t)i * 4);
  short ro[4], bo[4];
#pragma unroll
  for (int k = 0; k < 4; k++) { ro[k] = f2bf(r[k]); bo[k] = f2bf(b[k]); }
  *(unsigned long long*)(wrb + (size_t)i * 4) = *(unsigned long long*)ro;
  *(unsigned long long*)(wbb + (size_t)i * 4) = *(unsigned long long*)bo;
}

// ---------------- token-independent sums S0w[l][5], T0d[l][4] ---------------
__global__ __launch_bounds__(64) void prep_sums(
    const float* __restrict__ W_m, const float* __restrict__ W_r,
    const float* __restrict__ W_b, const float* __restrict__ dyn_gamma,
    float* __restrict__ S0w, float* __restrict__ T0d) {
  const int l = blockIdx.x;
  const int lane = threadIdx.x;
  float s[5] = {0, 0, 0, 0, 0}, t[4] = {0, 0, 0, 0};
  for (int d = lane; d < DD; d += 64) {
    const float g = dyn_gamma[l * DD + d];
    s[0] += g * W_m[l * DD + d];
    f32x4 r = *(const f32x4*)(W_r + ((size_t)l * DD + d) * 4);
    f32x4 b = *(const f32x4*)(W_b + ((size_t)l * DD + d) * 4);
#pragma unroll
    for (int m = 0; m < 4; m++) { s[1 + m] += g * r[m]; t[m] += g * b[m]; }
  }
#pragma unroll
  for (int m = 0; m < 5; m++) s[m] = wred(s[m]);
#pragma unroll
  for (int n = 0; n < 4; n++) t[n] = wred(t[n]);
  if (lane == 0) {
#pragma unroll
    for (int m = 0; m < 5; m++) S0w[l * 5 + m] = s[m];
#pragma unroll
    for (int n = 0; n < 4; n++) T0d[l * 4 + n] = t[n];
  }
}

// ---------------- transpose Wblk[l][d][e] (f32) -> Wt[l][e][d] (bf16) -------
__global__ __launch_bounds__(256) void transpose_wblk(
    const float* __restrict__ W, short* __restrict__ Wt) {
  __shared__ float tile[64][65];
  const int blk = blockIdx.z;
  const int c0 = blockIdx.x * 64;
  const int r0 = blockIdx.y * 64;
  const float* Ws = W + (size_t)blk * DD * DD;
  short* Wd = Wt + (size_t)blk * DD * DD;
  const int tx = threadIdx.x & 63, ty = threadIdx.x >> 6;
#pragma unroll
  for (int r = 0; r < 16; r++) {
    const int row = ty + r * 4;
    tile[row][tx] = Ws[(size_t)(r0 + row) * DD + c0 + tx];
  }
  __syncthreads();
#pragma unroll
  for (int r = 0; r < 16; r++) {
    const int row = ty + r * 4;
    Wd[(size_t)(c0 + row) * DD + r0 + tx] = f2bf(tile[tx][row]);
  }
}

// ---------------- width connections, block 0 (reads x f32) ------------------
// 1 wave per token (R2 structure); identical-rows col-sum trick.
__global__ __launch_bounds__(256) void width0_kernel(
    const float* __restrict__ x, short* __restrict__ Hst,
    short* __restrict__ hnorm, const float* __restrict__ A_m,
    const float* __restrict__ A_r, const float* __restrict__ W_m,
    const short* __restrict__ wrb, const float* __restrict__ s_a,
    const float* __restrict__ dyn_gamma, const float* __restrict__ norm_gamma,
    const float* __restrict__ norm_beta, const float* __restrict__ S0w) {
  const int wave = threadIdx.x >> 6;
  const int lane = threadIdx.x & 63;
  const int tok = blockIdx.x * 4 + wave;
  const int blk = 0;
  const float* dg = dyn_gamma + blk * DD;
  const float* wm = W_m + blk * DD;
  const short* wr = wrb + (size_t)blk * DD * 4;

  bf16x8 hreg[4];  // all N rows identical at block 0
  const float* xr = x + (size_t)tok * DD;
#pragma unroll
  for (int j = 0; j < 4; j++) {
    const int d0 = lane * 8 + j * 512;
    f32x4 a = *(const f32x4*)(xr + d0);
    f32x4 b = *(const f32x4*)(xr + d0 + 4);
    bf16x8 p;
#pragma unroll
    for (int q = 0; q < 4; q++) { p[q] = f2bf(a[q]); p[4 + q] = f2bf(b[q]); }
    hreg[j] = p;
  }

  float sH = 0, sH2 = 0, S1[5] = {0, 0, 0, 0, 0};
#pragma unroll
  for (int j = 0; j < 4; j++) {
    const int d0 = lane * 8 + j * 512;
    f32x4 g0 = *(const f32x4*)(dg + d0), g1 = *(const f32x4*)(dg + d0 + 4);
    f32x4 m0 = *(const f32x4*)(wm + d0), m1 = *(const f32x4*)(wm + d0 + 4);
    bf16x8 wv[4];
#pragma unroll
    for (int p = 0; p < 4; p++)
      wv[p] = *(const bf16x8*)(wr + (size_t)(d0 + 2 * p) * 4);
#pragma unroll
    for (int q = 0; q < 8; q++) {
      const float g = (q < 4) ? g0[q] : g1[q - 4];
      const float wmv = (q < 4) ? m0[q] : m1[q - 4];
      const float hv = bf2f(hreg[j][q]);
      sH += hv; sH2 += hv * hv;
      const float hg = hv * g;
      S1[0] += hg * wmv;
#pragma unroll
      for (int m = 0; m < 4; m++)
        S1[1 + m] += hg * bf2f(wv[q >> 1][(q & 1) * 4 + m]);
    }
  }
  sH = wred(sH); sH2 = wred(sH2);
#pragma unroll
  for (int m = 0; m < 5; m++) S1[m] = wred(S1[m]);

  const float sa = s_a[blk];
  const float mu0 = sH * (1.f / DD);
  const float inv0 = rsqrtf(sH2 * (1.f / DD) - mu0 * mu0 + EPSF);
  float amSum = 0.f, arCol[NN] = {0, 0, 0, 0};
  {
    const float t0 = tanhf(inv0 * (S1[0] - mu0 * S0w[blk * 5 + 0]));
    float tm[NN];
#pragma unroll
    for (int m = 0; m < NN; m++)
      tm[m] = tanhf(inv0 * (S1[1 + m] - mu0 * S0w[blk * 5 + 1 + m]));
#pragma unroll
    for (int n = 0; n < NN; n++) {
      amSum += A_m[blk * NN + n] + sa * t0;
#pragma unroll
      for (int m = 0; m < NN; m++)
        arCol[m] += A_r[blk * NN * NN + n * NN + m] + sa * tm[m];
    }
  }

  short* Ho = Hst + (size_t)tok * NN * DD;
  float hbuf[4][8];
  float sh = 0.f, sh2 = 0.f;
#pragma unroll
  for (int j = 0; j < 4; j++) {
    const int d0 = lane * 8 + j * 512;
    bf16x8 outp[NN];
#pragma unroll
    for (int q = 0; q < 8; q++) {
      const float hv = bf2f(hreg[j][q]);
      const float a0 = hv * amSum;
      hbuf[j][q] = a0; sh += a0; sh2 += a0 * a0;
#pragma unroll
      for (int m = 0; m < NN; m++) outp[m][q] = f2bf(hv * arCol[m]);
    }
#pragma unroll
    for (int m = 0; m < NN; m++) *(bf16x8*)(Ho + m * DD + d0) = outp[m];
  }
  sh = wred(sh); sh2 = wred(sh2);
  const float mu = sh * (1.f / DD);
  const float inv = rsqrtf(sh2 * (1.f / DD) - mu * mu + EPSF);
  const float* ng = norm_gamma + blk * DD;
  const float* nb = norm_beta + blk * DD;
  short* hn = hnorm + (size_t)tok * DD;
#pragma unroll
  for (int j = 0; j < 4; j++) {
    const int d0 = lane * 8 + j * 512;
    f32x4 g0 = *(const f32x4*)(ng + d0), g1 = *(const f32x4*)(ng + d0 + 4);
    f32x4 b0 = *(const f32x4*)(nb + d0), b1 = *(const f32x4*)(nb + d0 + 4);
    bf16x8 o;
#pragma unroll
    for (int q = 0; q < 8; q++) {
      const float g = (q < 4) ? g0[q] : g1[q - 4];
      const float b = (q < 4) ? b0[q] : b1[q - 4];
      o[q] = f2bf((hbuf[j][q] - mu) * inv * g + b);
    }
    *(bf16x8*)(hn + d0) = o;
  }
}

// ---------------- block GEMM: h2 = hnorm @ Wblk^T + bias --------------------
__global__ __launch_bounds__(256) void gemm_kernel(
    const short* __restrict__ A, const short* __restrict__ Bt,
    const float* __restrict__ bias, short* __restrict__ C) {
  __shared__ short lA[2][128 * 64];
  __shared__ short lB[2][128 * 64];
  const int tid = threadIdx.x;
  const int lane = tid & 63;
  const int wave = tid >> 6;
  const int m0 = blockIdx.x * 128, n0 = blockIdx.y * 128;
  const int wm = wave >> 1, wn = wave & 1;

  f32x4 acc[4][4] = {};

#define STAGE(buf, kt)                                                        \
  {                                                                           \
    const int k0 = (kt) * 64;                                                 \
    _Pragma("unroll") for (int c = 0; c < 4; c++) {                           \
      const int idx = c * 256 + tid;                                          \
      const int row = idx >> 3;                                               \
      const int colsw = (((idx & 7) ^ (row & 7)) * 8);                        \
      ld16(A + (size_t)(m0 + row) * DD + k0 + colsw,                          \
           (char*)&lA[buf][0] + idx * 16);                                    \
      ld16(Bt + (size_t)(n0 + row) * DD + k0 + colsw,                         \
           (char*)&lB[buf][0] + idx * 16);                                    \
    }                                                                         \
  }

  STAGE(0, 0);
  __syncthreads();

  for (int kt = 0; kt < 32; ++kt) {
    const int cur = kt & 1;
    if (kt < 31) STAGE(cur ^ 1, kt + 1);
    const char* bufA = (const char*)&lA[cur][0];
    const char* bufB = (const char*)&lB[cur][0];
#pragma unroll
    for (int kk = 0; kk < 2; ++kk) {
      const int gsw = (kk * 64 + (lane >> 4) * 16) ^ ((lane & 7) << 4);
      bf16x8 af[4], bfr[4];
#pragma unroll
      for (int m = 0; m < 4; m++) {
        const int r = wm * 64 + m * 16 + (lane & 15);
        af[m] = *(const bf16x8*)(bufA + r * 128 + gsw);
      }
#pragma unroll
      for (int n = 0; n < 4; n++) {
        const int r = wn * 64 + n * 16 + (lane & 15);
        bfr[n] = *(const bf16x8*)(bufB + r * 128 + gsw);
      }
#pragma unroll
      for (int m = 0; m < 4; m++)
#pragma unroll
        for (int n = 0; n < 4; n++)
          acc[m][n] = __builtin_amdgcn_mfma_f32_16x16x32_bf16(
              af[m], bfr[n], acc[m][n], 0, 0, 0);
    }
    __syncthreads();
  }
#undef STAGE

#pragma unroll
  for (int n = 0; n < 4; n++) {
    const int col = n0 + wn * 64 + n * 16 + (lane & 15);
    const float bv = bias[col];
#pragma unroll
    for (int m = 0; m < 4; m++) {
      const int rbase = m0 + wm * 64 + m * 16 + ((lane >> 4) << 2);
#pragma unroll
      for (int j = 0; j < 4; j++)
        C[(size_t)(rbase + j) * DD + col] = f2bf(acc[m][n][j] + bv);
    }
  }
}

// ---------------- fused depth(blk) + width(blk+1), 1 wave per token ---------
__global__ __launch_bounds__(256) void fused_dw(
    const short* __restrict__ h2, short* __restrict__ Hst,
    short* __restrict__ hnorm, const float* __restrict__ Bp,
    const short* __restrict__ wbb, const float* __restrict__ s_b,
    const float* __restrict__ A_m, const float* __restrict__ A_r,
    const float* __restrict__ W_m, const short* __restrict__ wrb,
    const float* __restrict__ s_a, const float* __restrict__ dyn_gamma,
    const float* __restrict__ norm_gamma, const float* __restrict__ norm_beta,
    const float* __restrict__ S0w, const float* __restrict__ T0d, int blk) {
  const int wave = threadIdx.x >> 6;
  const int lane = threadIdx.x & 63;
  const int tok = blockIdx.x * 4 + wave;
  const int nblk = blk + 1;
  const short* hr = h2 + (size_t)tok * DD;
  short* Ho = Hst + (size_t)tok * NN * DD;

  // ---- issue all big loads early ----
  bf16x8 h2r[4], hold[NN][4];
#pragma unroll
  for (int j = 0; j < 4; j++) {
    const int d0 = lane * 8 + j * 512;
    h2r[j] = *(const bf16x8*)(hr + d0);
#pragma unroll
    for (int n = 0; n < NN; n++)
      hold[n][j] = *(const bf16x8*)(Ho + n * DD + d0);
  }

  // ---- depth stats on h2 ----
  const float* dgd = dyn_gamma + blk * DD;
  const short* wb = wbb + (size_t)blk * DD * 4;
  float s1 = 0.f, s2 = 0.f, T1[NN] = {0, 0, 0, 0};
#pragma unroll
  for (int j = 0; j < 4; j++) {
    const int d0 = lane * 8 + j * 512;
    f32x4 g0 = *(const f32x4*)(dgd + d0), g1 = *(const f32x4*)(dgd + d0 + 4);
    bf16x8 wv[4];
#pragma unroll
    for (int p = 0; p < 4; p++)
      wv[p] = *(const bf16x8*)(wb + (size_t)(d0 + 2 * p) * 4);
#pragma unroll
    for (int q = 0; q < 8; q++) {
      const float g = (q < 4) ? g0[q] : g1[q - 4];
      const float hv = bf2f(h2r[j][q]);
      s1 += hv; s2 += hv * hv;
      const float hg = hv * g;
#pragma unroll
      for (int n = 0; n < NN; n++)
        T1[n] += hg * bf2f(wv[q >> 1][(q & 1) * 4 + n]);
    }
  }
  s1 = wred(s1); s2 = wred(s2);
#pragma unroll
  for (int n = 0; n < NN; n++) T1[n] = wred(T1[n]);
  float Bv[NN];
  {
    const float mu = s1 * (1.f / DD);
    const float inv = rsqrtf(s2 * (1.f / DD) - mu * mu + EPSF);
    const float sb = s_b[blk];
#pragma unroll
    for (int n = 0; n < NN; n++)
      Bv[n] = Bp[blk * NN + n] +
              sb * tanhf(inv * (T1[n] - mu * T0d[blk * NN + n]));
  }
  // ---- H' = H + h2 * Bv ----
#pragma unroll
  for (int n = 0; n < NN; n++)
#pragma unroll
    for (int j = 0; j < 4; j++) {
      bf16x8 o;
#pragma unroll
      for (int q = 0; q < 8; q++)
        o[q] = f2bf(bf2f(hold[n][j][q]) + bf2f(h2r[j][q]) * Bv[n]);
      hold[n][j] = o;
    }

  // ---- width stats of block nblk on H' ----
  const float* dg = dyn_gamma + nblk * DD;
  const float* wm = W_m + nblk * DD;
  const short* wr = wrb + (size_t)nblk * DD * 4;
  float sH[NN] = {0, 0, 0, 0}, sH2[NN] = {0, 0, 0, 0};
  float S1[NN][5];
#pragma unroll
  for (int n = 0; n < NN; n++)
#pragma unroll
    for (int m = 0; m < 5; m++) S1[n][m] = 0.f;

#pragma unroll
  for (int j = 0; j < 4; j++) {
    const int d0 = lane * 8 + j * 512;
    f32x4 g0 = *(const f32x4*)(dg + d0), g1 = *(const f32x4*)(dg + d0 + 4);
    f32x4 m0 = *(const f32x4*)(wm + d0), m1 = *(const f32x4*)(wm + d0 + 4);
    bf16x8 wv[4];
#pragma unroll
    for (int p = 0; p < 4; p++)
      wv[p] = *(const bf16x8*)(wr + (size_t)(d0 + 2 * p) * 4);
#pragma unroll
    for (int q = 0; q < 8; q++) {
      const float g = (q < 4) ? g0[q] : g1[q - 4];
      const float wmv = (q < 4) ? m0[q] : m1[q - 4];
      float gw[5];
      gw[0] = g * wmv;
#pragma unroll
      for (int m = 0; m < 4; m++)
        gw[1 + m] = g * bf2f(wv[q >> 1][(q & 1) * 4 + m]);
#pragma unroll
      for (int n = 0; n < NN; n++) {
        const float hv = bf2f(hold[n][j][q]);
        sH[n] += hv; sH2[n] += hv * hv;
#pragma unroll
        for (int m = 0; m < 5; m++) S1[n][m] += hv * gw[m];
      }
    }
  }
#pragma unroll
  for (int n = 0; n < NN; n++) { sH[n] = wred(sH[n]); sH2[n] = wred(sH2[n]); }
#pragma unroll
  for (int n = 0; n < NN; n++)
#pragma unroll
    for (int m = 0; m < 5; m++) S1[n][m] = wred(S1[n][m]);

  const float sa = s_a[nblk];
  float Am[NN], Ar[NN][NN];
#pragma unroll
  for (int n = 0; n < NN; n++) {
    const float mu = sH[n] * (1.f / DD);
    const float var = sH2[n] * (1.f / DD) - mu * mu;
    const float inv = rsqrtf(var + EPSF);
    Am[n] = A_m[nblk * NN + n] +
            sa * tanhf(inv * (S1[n][0] - mu * S0w[nblk * 5 + 0]));
#pragma unroll
    for (int m = 0; m < NN; m++)
      Ar[n][m] = A_r[nblk * NN * NN + n * NN + m] +
                 sa * tanhf(inv * (S1[n][1 + m] - mu * S0w[nblk * 5 + 1 + m]));
  }

  float hbuf[4][8];
  float sh = 0.f, sh2 = 0.f;
#pragma unroll
  for (int j = 0; j < 4; j++) {
    const int d0 = lane * 8 + j * 512;
    bf16x8 outp[NN];
#pragma unroll
    for (int q = 0; q < 8; q++) {
      float a0 = 0.f, am0 = 0.f, am1 = 0.f, am2 = 0.f, am3 = 0.f;
#pragma unroll
      for (int n = 0; n < NN; n++) {
        const float hv = bf2f(hold[n][j][q]);
        a0 += hv * Am[n];
        am0 += hv * Ar[n][0];
        am1 += hv * Ar[n][1];
        am2 += hv * Ar[n][2];
        am3 += hv * Ar[n][3];
      }
      hbuf[j][q] = a0; sh += a0; sh2 += a0 * a0;
      outp[0][q] = f2bf(am0); outp[1][q] = f2bf(am1);
      outp[2][q] = f2bf(am2); outp[3][q] = f2bf(am3);
    }
#pragma unroll
    for (int m = 0; m < NN; m++) *(bf16x8*)(Ho + m * DD + d0) = outp[m];
  }
  sh = wred(sh); sh2 = wred(sh2);
  const float mu = sh * (1.f / DD);
  const float inv = rsqrtf(sh2 * (1.f / DD) - mu * mu + EPSF);
  const float* ng = norm_gamma + nblk * DD;
  const float* nb = norm_beta + nblk * DD;
  short* hn = hnorm + (size_t)tok * DD;
#pragma unroll
  for (int j = 0; j < 4; j++) {
    const int d0 = lane * 8 + j * 512;
    f32x4 g0 = *(const f32x4*)(ng + d0), g1 = *(const f32x4*)(ng + d0 + 4);
    f32x4 b0 = *(const f32x4*)(nb + d0), b1 = *(const f32x4*)(nb + d0 + 4);
    bf16x8 o;
#pragma unroll
    for (int q = 0; q < 8; q++) {
      const float g = (q < 4) ? g0[q] : g1[q - 4];
      const float b = (q < 4) ? b0[q] : b1[q - 4];
      o[q] = f2bf((hbuf[j][q] - mu) * inv * g + b);
    }
    *(bf16x8*)(hn + d0) = o;
  }
}

// ---------------- final depth (block 3) + output sum ------------------------
__global__ __launch_bounds__(256) void depth_last(
    const short* __restrict__ h2, const short* __restrict__ Hst,
    float* __restrict__ out, const float* __restrict__ Bp,
    const short* __restrict__ wbb, const float* __restrict__ s_b,
    const float* __restrict__ dyn_gamma, const float* __restrict__ T0d,
    int blk) {
  const int wave = threadIdx.x >> 6;
  const int lane = threadIdx.x & 63;
  const int tok = blockIdx.x * 4 + wave;
  const short* hr = h2 + (size_t)tok * DD;
  const float* dg = dyn_gamma + blk * DD;
  const short* wb = wbb + (size_t)blk * DD * 4;

  bf16x8 h2r[4];
  float s1 = 0.f, s2 = 0.f, T1[NN] = {0, 0, 0, 0};
#pragma unroll
  for (int j = 0; j < 4; j++) {
    const int d0 = lane * 8 + j * 512;
    h2r[j] = *(const bf16x8*)(hr + d0);
    f32x4 g0 = *(const f32x4*)(dg + d0), g1 = *(const f32x4*)(dg + d0 + 4);
    bf16x8 wv[4];
#pragma unroll
    for (int p = 0; p < 4; p++)
      wv[p] = *(const bf16x8*)(wb + (size_t)(d0 + 2 * p) * 4);
#pragma unroll
    for (int q = 0; q < 8; q++) {
      const float g = (q < 4) ? g0[q] : g1[q - 4];
      const float hv = bf2f(h2r[j][q]);
      s1 += hv; s2 += hv * hv;
      const float hg = hv * g;
#pragma unroll
      for (int n = 0; n < NN; n++)
        T1[n] += hg * bf2f(wv[q >> 1][(q & 1) * 4 + n]);
    }
  }
  s1 = wred(s1); s2 = wred(s2);
#pragma unroll
  for (int n = 0; n < NN; n++) T1[n] = wred(T1[n]);
  const float mu = s1 * (1.f / DD);
  const float inv = rsqrtf(s2 * (1.f / DD) - mu * mu + EPSF);
  const float sb = s_b[blk];
  float bsum = 0.f;
#pragma unroll
  for (int n = 0; n < NN; n++)
    bsum += Bp[blk * NN + n] + sb * tanhf(inv * (T1[n] - mu * T0d[blk * NN + n]));

  const short* Ho = Hst + (size_t)tok * NN * DD;
  float* orow = out + (size_t)tok * DD;
#pragma unroll
  for (int j = 0; j < 4; j++) {
    const int d0 = lane * 8 + j * 512;
    bf16x8 hrow[NN];
#pragma unroll
    for (int n = 0; n < NN; n++) hrow[n] = *(const bf16x8*)(Ho + n * DD + d0);
    f32x4 o0, o1;
#pragma unroll
    for (int q = 0; q < 8; q++) {
      const float hv = bf2f(h2r[j][q]);
      float s = hv * bsum;
#pragma unroll
      for (int n = 0; n < NN; n++) s += bf2f(hrow[n][q]);
      if (q < 4) o0[q] = s; else o1[q - 4] = s;
    }
    *(f32x4*)(orow + d0) = o0;
    *(f32x4*)(orow + d0 + 4) = o1;
  }
}

extern "C" void kernel_launch(void* const* d_in, const int* in_sizes, int n_in,
                              void* d_out, int out_size, void* d_ws,
                              size_t ws_size, hipStream_t stream) {
  const float* x = (const float*)d_in[0];
  const float* A_m = (const float*)d_in[1];
  const float* A_r = (const float*)d_in[2];
  const float* Bp = (const float*)d_in[3];
  const float* W_m = (const float*)d_in[4];
  const float* W_r = (const float*)d_in[5];
  const float* W_b = (const float*)d_in[6];
  const float* s_a = (const float*)d_in[7];
  const float* s_b = (const float*)d_in[8];
  const float* dyn_gamma = (const float*)d_in[9];
  const float* norm_gamma = (const float*)d_in[10];
  const float* norm_beta = (const float*)d_in[11];
  const float* Wblk = (const float*)d_in[12];
  const float* bblk = (const float*)d_in[13];
  float* out = (float*)d_out;

  char* ws = (char*)d_ws;
  short* Hst = (short*)(ws);                      // [0, 64 MiB)
  short* hnorm = (short*)(ws + 67108864);         // [64, 80)
  short* h2 = (short*)(ws + 83886080);            // [80, 96)
  short* wrb = (short*)(ws + 100663296);          // [96 MiB +0, +64K)
  short* wbb = (short*)(ws + 100663296 + 65536);  // +64K
  float* S0w = (float*)(ws + 100663296 + 131072);
  float* T0d = (float*)(ws + 100663296 + 131072 + 128);
  // Wt lives in d_out: recomputed every call, overwritten by depth_last
  short* Wt = (short*)d_out;

  dim3 tb(256);
  prep_pack<<<32, tb, 0, stream>>>(W_r, W_b, wrb, wbb);
  prep_sums<<<4, dim3(64), 0, stream>>>(W_m, W_r, W_b, dyn_gamma, S0w, T0d);
  transpose_wblk<<<dim3(32, 32, 4), tb, 0, stream>>>(Wblk, Wt);
  width0_kernel<<<1024, tb, 0, stream>>>(x, Hst, hnorm, A_m, A_r, W_m, wrb,
                                         s_a, dyn_gamma, norm_gamma, norm_beta,
                                         S0w);
  for (int i = 0; i < LL; i++) {
    gemm_kernel<<<dim3(32, 16), tb, 0, stream>>>(
        hnorm, Wt + (size_t)i * DD * DD, bblk + i * DD, h2);
    if (i < LL - 1)
      fused_dw<<<1024, tb, 0, stream>>>(h2, Hst, hnorm, Bp, wbb, s_b, A_m, A_r,
                                        W_m, wrb, s_a, dyn_gamma, norm_gamma,
                                        norm_beta, S0w, T0d, i);
    else
      depth_last<<<1024, tb, 0, stream>>>(h2, Hst, out, Bp, wbb, s_b,
                                          dyn_gamma, T0d, i);
  }
}

// Round 5
// 390.770 us; speedup vs baseline: 1.6431x; 1.0032x over previous
//
#include <hip/hip_runtime.h>
#include <hip/hip_bf16.h>

// HCNet: L=4 hyper-connection blocks, N=4, D=2048, B*T=4096 tokens.
// R5: algebraic deletions. (1) pre-norm LN folded into GEMM: Wt'=gamma*W^T,
// epilogue h2 = inv*acc - mu*inv*E1 + E0; fused_dw emits unnormalized h +
// per-token (inv, mu*inv). (2) dyn_gamma pre-multiplied into bf16 tables
// gwm/gwr/gwb. (3) native __float2bfloat16 (v_cvt_pk) instead of manual RNE.

#define DD 2048
#define NN 4
#define LL 4
#define NTOK 4096
#define EPSF 1e-5f

typedef __attribute__((ext_vector_type(8))) short bf16x8;
typedef __attribute__((ext_vector_type(4))) float f32x4;
typedef __attribute__((ext_vector_type(2))) float f32x2;

__device__ __forceinline__ float bf2f(short u) {
  union { unsigned int i; float f; } v;
  v.i = ((unsigned int)(unsigned short)u) << 16;
  return v.f;
}
__device__ __forceinline__ short f2bf(float f) {
  __hip_bfloat16 h = __float2bfloat16(f);
  short s;
  __builtin_memcpy(&s, &h, 2);
  return s;
}
__device__ __forceinline__ float wred(float v) {
#pragma unroll
  for (int off = 32; off > 0; off >>= 1) v += __shfl_xor(v, off, 64);
  return v;
}
__device__ __forceinline__ void ld16(const void* g, void* l) {
  __builtin_amdgcn_global_load_lds(
      (const __attribute__((address_space(1))) void*)g,
      (__attribute__((address_space(3))) void*)l, 16, 0, 0);
}

// ---------------- prep: gamma-scaled bf16 tables + beta/gamma ratio ---------
// gwm[l][D] = dyn_g*W_m ; gwr[l][D][4] = dyn_g*W_r ; gwb[l][D][4] = dyn_g*W_b
// rb[l][D] = norm_beta / norm_gamma
__global__ __launch_bounds__(256) void prep_pack(
    const float* __restrict__ W_m, const float* __restrict__ W_r,
    const float* __restrict__ W_b, const float* __restrict__ dyn_gamma,
    const float* __restrict__ norm_gamma, const float* __restrict__ norm_beta,
    short* __restrict__ gwm, short* __restrict__ gwr, short* __restrict__ gwb,
    float* __restrict__ rb) {
  const int i = blockIdx.x * 256 + threadIdx.x;  // over L*D = 8192
  const float g = dyn_gamma[i];
  gwm[i] = f2bf(g * W_m[i]);
  f32x4 r = *(const f32x4*)(W_r + (size_t)i * 4);
  f32x4 b = *(const f32x4*)(W_b + (size_t)i * 4);
  short ro[4], bo[4];
#pragma unroll
  for (int k = 0; k < 4; k++) { ro[k] = f2bf(g * r[k]); bo[k] = f2bf(g * b[k]); }
  *(unsigned long long*)(gwr + (size_t)i * 4) = *(unsigned long long*)ro;
  *(unsigned long long*)(gwb + (size_t)i * 4) = *(unsigned long long*)bo;
  rb[i] = norm_beta[i] / norm_gamma[i];
}

// ---------------- token-independent sums S0w[l][5], T0d[l][4] ---------------
__global__ __launch_bounds__(64) void prep_sums(
    const float* __restrict__ W_m, const float* __restrict__ W_r,
    const float* __restrict__ W_b, const float* __restrict__ dyn_gamma,
    float* __restrict__ S0w, float* __restrict__ T0d) {
  const int l = blockIdx.x;
  const int lane = threadIdx.x;
  float s[5] = {0, 0, 0, 0, 0}, t[4] = {0, 0, 0, 0};
  for (int d = lane; d < DD; d += 64) {
    const float g = dyn_gamma[l * DD + d];
    s[0] += g * W_m[l * DD + d];
    f32x4 r = *(const f32x4*)(W_r + ((size_t)l * DD + d) * 4);
    f32x4 b = *(const f32x4*)(W_b + ((size_t)l * DD + d) * 4);
#pragma unroll
    for (int m = 0; m < 4; m++) { s[1 + m] += g * r[m]; t[m] += g * b[m]; }
  }
#pragma unroll
  for (int m = 0; m < 5; m++) s[m] = wred(s[m]);
#pragma unroll
  for (int n = 0; n < 4; n++) t[n] = wred(t[n]);
  if (lane == 0) {
#pragma unroll
    for (int m = 0; m < 5; m++) S0w[l * 5 + m] = s[m];
#pragma unroll
    for (int n = 0; n < 4; n++) T0d[l * 4 + n] = t[n];
  }
}

// ------- transpose Wblk[l][d][e] (f32) -> Wt[l][e][d] = norm_g[d]*W (bf16) --
__global__ __launch_bounds__(256) void transpose_wblk(
    const float* __restrict__ W, const float* __restrict__ norm_gamma,
    short* __restrict__ Wt) {
  __shared__ float tile[64][65];
  const int blk = blockIdx.z;
  const int c0 = blockIdx.x * 64;
  const int r0 = blockIdx.y * 64;
  const float* Ws = W + (size_t)blk * DD * DD;
  short* Wd = Wt + (size_t)blk * DD * DD;
  const int tx = threadIdx.x & 63, ty = threadIdx.x >> 6;
#pragma unroll
  for (int r = 0; r < 16; r++) {
    const int row = ty + r * 4;
    tile[row][tx] = Ws[(size_t)(r0 + row) * DD + c0 + tx];
  }
  const float gsc = norm_gamma[blk * DD + r0 + tx];  // d = r0+tx per thread
  __syncthreads();
#pragma unroll
  for (int r = 0; r < 16; r++) {
    const int row = ty + r * 4;
    Wd[(size_t)(c0 + row) * DD + r0 + tx] = f2bf(tile[tx][row] * gsc);
  }
}

// ---------------- row sums of Wt': E1 = sum_d Wt', E0 = sum_d rb*Wt' + bias -
__global__ __launch_bounds__(256) void row_sums(
    const short* __restrict__ Wt, const float* __restrict__ rb,
    const float* __restrict__ bblk, float* __restrict__ E0,
    float* __restrict__ E1) {
  const int l = blockIdx.y;
  const int e = blockIdx.x * 4 + (threadIdx.x >> 6);
  const int lane = threadIdx.x & 63;
  const short* row = Wt + ((size_t)l * DD + e) * DD;
  const float* rbl = rb + l * DD;
  float s1 = 0.f, s0 = 0.f;
#pragma unroll
  for (int it = 0; it < 4; it++) {
    const int d0 = lane * 8 + it * 512;
    bf16x8 w = *(const bf16x8*)(row + d0);
    f32x4 r0 = *(const f32x4*)(rbl + d0), r1 = *(const f32x4*)(rbl + d0 + 4);
#pragma unroll
    for (int q = 0; q < 8; q++) {
      const float wq = bf2f(w[q]);
      s1 += wq;
      s0 += wq * ((q < 4) ? r0[q] : r1[q - 4]);
    }
  }
  s1 = wred(s1); s0 = wred(s0);
  if (lane == 0) {
    E1[l * DD + e] = s1;
    E0[l * DD + e] = s0 + bblk[l * DD + e];
  }
}

// ---------------- width connections, block 0 (reads x f32) ------------------
__global__ __launch_bounds__(256) void width0_kernel(
    const float* __restrict__ x, short* __restrict__ Hst,
    short* __restrict__ hout, f32x2* __restrict__ tst,
    const float* __restrict__ A_m, const float* __restrict__ A_r,
    const short* __restrict__ gwm, const short* __restrict__ gwr,
    const float* __restrict__ s_a, const float* __restrict__ S0w) {
  const int wave = threadIdx.x >> 6;
  const int lane = threadIdx.x & 63;
  const int tok = blockIdx.x * 4 + wave;
  const int blk = 0;
  const short* wm = gwm + blk * DD;
  const short* wr = gwr + (size_t)blk * DD * 4;

  bf16x8 hreg[4];  // all N rows identical at block 0
  const float* xr = x + (size_t)tok * DD;
#pragma unroll
  for (int j = 0; j < 4; j++) {
    const int d0 = lane * 8 + j * 512;
    f32x4 a = *(const f32x4*)(xr + d0);
    f32x4 b = *(const f32x4*)(xr + d0 + 4);
    bf16x8 p;
#pragma unroll
    for (int q = 0; q < 4; q++) { p[q] = f2bf(a[q]); p[4 + q] = f2bf(b[q]); }
    hreg[j] = p;
  }

  float sH = 0, sH2 = 0, S1[5] = {0, 0, 0, 0, 0};
#pragma unroll
  for (int j = 0; j < 4; j++) {
    const int d0 = lane * 8 + j * 512;
    bf16x8 mv = *(const bf16x8*)(wm + d0);
    bf16x8 wv[4];
#pragma unroll
    for (int p = 0; p < 4; p++)
      wv[p] = *(const bf16x8*)(wr + (size_t)(d0 + 2 * p) * 4);
#pragma unroll
    for (int q = 0; q < 8; q++) {
      const float hv = bf2f(hreg[j][q]);
      sH += hv; sH2 += hv * hv;
      S1[0] += hv * bf2f(mv[q]);
#pragma unroll
      for (int m = 0; m < 4; m++)
        S1[1 + m] += hv * bf2f(wv[q >> 1][(q & 1) * 4 + m]);
    }
  }
  sH = wred(sH); sH2 = wred(sH2);
#pragma unroll
  for (int m = 0; m < 5; m++) S1[m] = wred(S1[m]);

  const float sa = s_a[blk];
  const float mu0 = sH * (1.f / DD);
  const float inv0 = rsqrtf(sH2 * (1.f / DD) - mu0 * mu0 + EPSF);
  float amSum = 0.f, arCol[NN] = {0, 0, 0, 0};
  {
    const float t0 = tanhf(inv0 * (S1[0] - mu0 * S0w[blk * 5 + 0]));
    float tm[NN];
#pragma unroll
    for (int m = 0; m < NN; m++)
      tm[m] = tanhf(inv0 * (S1[1 + m] - mu0 * S0w[blk * 5 + 1 + m]));
#pragma unroll
    for (int n = 0; n < NN; n++) {
      amSum += A_m[blk * NN + n] + sa * t0;
#pragma unroll
      for (int m = 0; m < NN; m++)
        arCol[m] += A_r[blk * NN * NN + n * NN + m] + sa * tm[m];
    }
  }

  short* Ho = Hst + (size_t)tok * NN * DD;
  short* hw = hout + (size_t)tok * DD;
  float sh = 0.f, sh2 = 0.f;
#pragma unroll
  for (int j = 0; j < 4; j++) {
    const int d0 = lane * 8 + j * 512;
    bf16x8 outp[NN], ho;
#pragma unroll
    for (int q = 0; q < 8; q++) {
      const float hv = bf2f(hreg[j][q]);
      const float a0 = hv * amSum;
      sh += a0; sh2 += a0 * a0;
      ho[q] = f2bf(a0);
#pragma unroll
      for (int m = 0; m < NN; m++) outp[m][q] = f2bf(hv * arCol[m]);
    }
    *(bf16x8*)(hw + d0) = ho;
#pragma unroll
    for (int m = 0; m < NN; m++) *(bf16x8*)(Ho + m * DD + d0) = outp[m];
  }
  sh = wred(sh); sh2 = wred(sh2);
  if (lane == 0) {
    const float mu = sh * (1.f / DD);
    const float inv = rsqrtf(sh2 * (1.f / DD) - mu * mu + EPSF);
    f32x2 t; t[0] = inv; t[1] = mu * inv;
    tst[tok] = t;
  }
}

// ---------------- block GEMM: h2 = LN-folded(h @ Wt') -----------------------
// epilogue: h2 = inv*acc - mu*inv*E1[col] + E0[col]
__global__ __launch_bounds__(256) void gemm_kernel(
    const short* __restrict__ A, const short* __restrict__ Bt,
    const f32x2* __restrict__ tst, const float* __restrict__ E0,
    const float* __restrict__ E1, short* __restrict__ C) {
  __shared__ short lA[2][128 * 64];
  __shared__ short lB[2][128 * 64];
  const int tid = threadIdx.x;
  const int lane = tid & 63;
  const int wave = tid >> 6;
  const int m0 = blockIdx.x * 128, n0 = blockIdx.y * 128;
  const int wm = wave >> 1, wn = wave & 1;

  f32x4 acc[4][4] = {};

#define STAGE(buf, kt)                                                        \
  {                                                                           \
    const int k0 = (kt) * 64;                                                 \
    _Pragma("unroll") for (int c = 0; c < 4; c++) {                           \
      const int idx = c * 256 + tid;                                          \
      const int row = idx >> 3;                                               \
      const int colsw = (((idx & 7) ^ (row & 7)) * 8);                        \
      ld16(A + (size_t)(m0 + row) * DD + k0 + colsw,                          \
           (char*)&lA[buf][0] + idx * 16);                                    \
      ld16(Bt + (size_t)(n0 + row) * DD + k0 + colsw,                         \
           (char*)&lB[buf][0] + idx * 16);                                    \
    }                                                                         \
  }

  STAGE(0, 0);
  __syncthreads();

  for (int kt = 0; kt < 32; ++kt) {
    const int cur = kt & 1;
    if (kt < 31) STAGE(cur ^ 1, kt + 1);
    const char* bufA = (const char*)&lA[cur][0];
    const char* bufB = (const char*)&lB[cur][0];
#pragma unroll
    for (int kk = 0; kk < 2; ++kk) {
      const int gsw = (kk * 64 + (lane >> 4) * 16) ^ ((lane & 7) << 4);
      bf16x8 af[4], bfr[4];
#pragma unroll
      for (int m = 0; m < 4; m++) {
        const int r = wm * 64 + m * 16 + (lane & 15);
        af[m] = *(const bf16x8*)(bufA + r * 128 + gsw);
      }
#pragma unroll
      for (int n = 0; n < 4; n++) {
        const int r = wn * 64 + n * 16 + (lane & 15);
        bfr[n] = *(const bf16x8*)(bufB + r * 128 + gsw);
      }
#pragma unroll
      for (int m = 0; m < 4; m++)
#pragma unroll
        for (int n = 0; n < 4; n++)
          acc[m][n] = __builtin_amdgcn_mfma_f32_16x16x32_bf16(
              af[m], bfr[n], acc[m][n], 0, 0, 0);
    }
    __syncthreads();
  }
#undef STAGE

  float e0c[4], e1c[4];
  int cols[4];
#pragma unroll
  for (int n = 0; n < 4; n++) {
    cols[n] = n0 + wn * 64 + n * 16 + (lane & 15);
    e0c[n] = E0[cols[n]];
    e1c[n] = E1[cols[n]];
  }
#pragma unroll
  for (int m = 0; m < 4; m++) {
    const int rbase = m0 + wm * 64 + m * 16 + ((lane >> 4) << 2);
#pragma unroll
    for (int j = 0; j < 4; j++) {
      const int row = rbase + j;
      const f32x2 iv = tst[row];
#pragma unroll
      for (int n = 0; n < 4; n++)
        C[(size_t)row * DD + cols[n]] =
            f2bf(iv[0] * acc[m][n][j] - iv[1] * e1c[n] + e0c[n]);
    }
  }
}

// ---------------- fused depth(blk) + width(blk+1), 1 wave per token ---------
__global__ __launch_bounds__(256) void fused_dw(
    const short* __restrict__ h2, short* __restrict__ Hst,
    short* __restrict__ hout, f32x2* __restrict__ tst,
    const float* __restrict__ Bp, const short* __restrict__ gwb,
    const float* __restrict__ s_b, const float* __restrict__ A_m,
    const float* __restrict__ A_r, const short* __restrict__ gwm,
    const short* __restrict__ gwr, const float* __restrict__ s_a,
    const float* __restrict__ S0w, const float* __restrict__ T0d, int blk) {
  const int wave = threadIdx.x >> 6;
  const int lane = threadIdx.x & 63;
  const int tok = blockIdx.x * 4 + wave;
  const int nblk = blk + 1;
  const short* hr = h2 + (size_t)tok * DD;
  short* Ho = Hst + (size_t)tok * NN * DD;

  // ---- issue all big loads early ----
  bf16x8 h2r[4], hold[NN][4];
#pragma unroll
  for (int j = 0; j < 4; j++) {
    const int d0 = lane * 8 + j * 512;
    h2r[j] = *(const bf16x8*)(hr + d0);
#pragma unroll
    for (int n = 0; n < NN; n++)
      hold[n][j] = *(const bf16x8*)(Ho + n * DD + d0);
  }

  // ---- depth stats on h2 (gwb = dyn_g*W_b pre-scaled) ----
  const short* wb = gwb + (size_t)blk * DD * 4;
  float s1 = 0.f, s2 = 0.f, T1[NN] = {0, 0, 0, 0};
#pragma unroll
  for (int j = 0; j < 4; j++) {
    const int d0 = lane * 8 + j * 512;
    bf16x8 wv[4];
#pragma unroll
    for (int p = 0; p < 4; p++)
      wv[p] = *(const bf16x8*)(wb + (size_t)(d0 + 2 * p) * 4);
#pragma unroll
    for (int q = 0; q < 8; q++) {
      const float hv = bf2f(h2r[j][q]);
      s1 += hv; s2 += hv * hv;
#pragma unroll
      for (int n = 0; n < NN; n++)
        T1[n] += hv * bf2f(wv[q >> 1][(q & 1) * 4 + n]);
    }
  }
  s1 = wred(s1); s2 = wred(s2);
#pragma unroll
  for (int n = 0; n < NN; n++) T1[n] = wred(T1[n]);
  float Bv[NN];
  {
    const float mu = s1 * (1.f / DD);
    const float inv = rsqrtf(s2 * (1.f / DD) - mu * mu + EPSF);
    const float sb = s_b[blk];
#pragma unroll
    for (int n = 0; n < NN; n++)
      Bv[n] = Bp[blk * NN + n] +
              sb * tanhf(inv * (T1[n] - mu * T0d[blk * NN + n]));
  }
  // ---- H' = H + h2 * Bv ----
#pragma unroll
  for (int n = 0; n < NN; n++)
#pragma unroll
    for (int j = 0; j < 4; j++) {
      bf16x8 o;
#pragma unroll
      for (int q = 0; q < 8; q++)
        o[q] = f2bf(bf2f(hold[n][j][q]) + bf2f(h2r[j][q]) * Bv[n]);
      hold[n][j] = o;
    }

  // ---- width stats of block nblk on H' (gwm/gwr pre-scaled) ----
  const short* wm = gwm + nblk * DD;
  const short* wr = gwr + (size_t)nblk * DD * 4;
  float sH[NN] = {0, 0, 0, 0}, sH2[NN] = {0, 0, 0, 0};
  float S1[NN][5];
#pragma unroll
  for (int n = 0; n < NN; n++)
#pragma unroll
    for (int m = 0; m < 5; m++) S1[n][m] = 0.f;

#pragma unroll
  for (int j = 0; j < 4; j++) {
    const int d0 = lane * 8 + j * 512;
    bf16x8 mv = *(const bf16x8*)(wm + d0);
    bf16x8 wv[4];
#pragma unroll
    for (int p = 0; p < 4; p++)
      wv[p] = *(const bf16x8*)(wr + (size_t)(d0 + 2 * p) * 4);
#pragma unroll
    for (int q = 0; q < 8; q++) {
      float gw[5];
      gw[0] = bf2f(mv[q]);
#pragma unroll
      for (int m = 0; m < 4; m++)
        gw[1 + m] = bf2f(wv[q >> 1][(q & 1) * 4 + m]);
#pragma unroll
      for (int n = 0; n < NN; n++) {
        const float hv = bf2f(hold[n][j][q]);
        sH[n] += hv; sH2[n] += hv * hv;
#pragma unroll
        for (int m = 0; m < 5; m++) S1[n][m] += hv * gw[m];
      }
    }
  }
#pragma unroll
  for (int n = 0; n < NN; n++) { sH[n] = wred(sH[n]); sH2[n] = wred(sH2[n]); }
#pragma unroll
  for (int n = 0; n < NN; n++)
#pragma unroll
    for (int m = 0; m < 5; m++) S1[n][m] = wred(S1[n][m]);

  const float sa = s_a[nblk];
  float Am[NN], Ar[NN][NN];
#pragma unroll
  for (int n = 0; n < NN; n++) {
    const float mu = sH[n] * (1.f / DD);
    const float var = sH2[n] * (1.f / DD) - mu * mu;
    const float inv = rsqrtf(var + EPSF);
    Am[n] = A_m[nblk * NN + n] +
            sa * tanhf(inv * (S1[n][0] - mu * S0w[nblk * 5 + 0]));
#pragma unroll
    for (int m = 0; m < NN; m++)
      Ar[n][m] = A_r[nblk * NN * NN + n * NN + m] +
                 sa * tanhf(inv * (S1[n][1 + m] - mu * S0w[nblk * 5 + 1 + m]));
  }

  short* hw = hout + (size_t)tok * DD;
  float sh = 0.f, sh2 = 0.f;
#pragma unroll
  for (int j = 0; j < 4; j++) {
    const int d0 = lane * 8 + j * 512;
    bf16x8 outp[NN], ho;
#pragma unroll
    for (int q = 0; q < 8; q++) {
      float a0 = 0.f, am0 = 0.f, am1 = 0.f, am2 = 0.f, am3 = 0.f;
#pragma unroll
      for (int n = 0; n < NN; n++) {
        const float hv = bf2f(hold[n][j][q]);
        a0 += hv * Am[n];
        am0 += hv * Ar[n][0];
        am1 += hv * Ar[n][1];
        am2 += hv * Ar[n][2];
        am3 += hv * Ar[n][3];
      }
      sh += a0; sh2 += a0 * a0;
      ho[q] = f2bf(a0);
      outp[0][q] = f2bf(am0); outp[1][q] = f2bf(am1);
      outp[2][q] = f2bf(am2); outp[3][q] = f2bf(am3);
    }
    *(bf16x8*)(hw + d0) = ho;
#pragma unroll
    for (int m = 0; m < NN; m++) *(bf16x8*)(Ho + m * DD + d0) = outp[m];
  }
  sh = wred(sh); sh2 = wred(sh2);
  if (lane == 0) {
    const float mu = sh * (1.f / DD);
    const float inv = rsqrtf(sh2 * (1.f / DD) - mu * mu + EPSF);
    f32x2 t; t[0] = inv; t[1] = mu * inv;
    tst[tok] = t;
  }
}

// ---------------- final depth (block 3) + output sum ------------------------
__global__ __launch_bounds__(256) void depth_last(
    const short* __restrict__ h2, const short* __restrict__ Hst,
    float* __restrict__ out, const float* __restrict__ Bp,
    const short* __restrict__ gwb, const float* __restrict__ s_b,
    const float* __restrict__ T0d, int blk) {
  const int wave = threadIdx.x >> 6;
  const int lane = threadIdx.x & 63;
  const int tok = blockIdx.x * 4 + wave;
  const short* hr = h2 + (size_t)tok * DD;
  const short* wb = gwb + (size_t)blk * DD * 4;

  bf16x8 h2r[4];
  float s1 = 0.f, s2 = 0.f, T1[NN] = {0, 0, 0, 0};
#pragma unroll
  for (int j = 0; j < 4; j++) {
    const int d0 = lane * 8 + j * 512;
    h2r[j] = *(const bf16x8*)(hr + d0);
    bf16x8 wv[4];
#pragma unroll
    for (int p = 0; p < 4; p++)
      wv[p] = *(const bf16x8*)(wb + (size_t)(d0 + 2 * p) * 4);
#pragma unroll
    for (int q = 0; q < 8; q++) {
      const float hv = bf2f(h2r[j][q]);
      s1 += hv; s2 += hv * hv;
#pragma unroll
      for (int n = 0; n < NN; n++)
        T1[n] += hv * bf2f(wv[q >> 1][(q & 1) * 4 + n]);
    }
  }
  s1 = wred(s1); s2 = wred(s2);
#pragma unroll
  for (int n = 0; n < NN; n++) T1[n] = wred(T1[n]);
  const float mu = s1 * (1.f / DD);
  const float inv = rsqrtf(s2 * (1.f / DD) - mu * mu + EPSF);
  const float sb = s_b[blk];
  float bsum = 0.f;
#pragma unroll
  for (int n = 0; n < NN; n++)
    bsum += Bp[blk * NN + n] + sb * tanhf(inv * (T1[n] - mu * T0d[blk * NN + n]));

  const short* Ho = Hst + (size_t)tok * NN * DD;
  float* orow = out + (size_t)tok * DD;
#pragma unroll
  for (int j = 0; j < 4; j++) {
    const int d0 = lane * 8 + j * 512;
    bf16x8 hrow[NN];
#pragma unroll
    for (int n = 0; n < NN; n++) hrow[n] = *(const bf16x8*)(Ho + n * DD + d0);
    f32x4 o0, o1;
#pragma unroll
    for (int q = 0; q < 8; q++) {
      const float hv = bf2f(h2r[j][q]);
      float s = hv * bsum;
#pragma unroll
      for (int n = 0; n < NN; n++) s += bf2f(hrow[n][q]);
      if (q < 4) o0[q] = s; else o1[q - 4] = s;
    }
    *(f32x4*)(orow + d0) = o0;
    *(f32x4*)(orow + d0 + 4) = o1;
  }
}

extern "C" void kernel_launch(void* const* d_in, const int* in_sizes, int n_in,
                              void* d_out, int out_size, void* d_ws,
                              size_t ws_size, hipStream_t stream) {
  const float* x = (const float*)d_in[0];
  const float* A_m = (const float*)d_in[1];
  const float* A_r = (const float*)d_in[2];
  const float* Bp = (const float*)d_in[3];
  const float* W_m = (const float*)d_in[4];
  const float* W_r = (const float*)d_in[5];
  const float* W_b = (const float*)d_in[6];
  const float* s_a = (const float*)d_in[7];
  const float* s_b = (const float*)d_in[8];
  const float* dyn_gamma = (const float*)d_in[9];
  const float* norm_gamma = (const float*)d_in[10];
  const float* norm_beta = (const float*)d_in[11];
  const float* Wblk = (const float*)d_in[12];
  const float* bblk = (const float*)d_in[13];
  float* out = (float*)d_out;

  char* ws = (char*)d_ws;
  short* Hst = (short*)(ws);                      // [0, 64 MiB)
  short* hbuf = (short*)(ws + 67108864);          // [64, 80) unnormalized h
  short* h2 = (short*)(ws + 83886080);            // [80, 96)
  char* aux = ws + 100663296;                     // [96 MiB, ...)
  short* gwm = (short*)(aux);                     // 16 KiB
  short* gwr = (short*)(aux + 16384);             // 64 KiB
  short* gwb = (short*)(aux + 16384 + 65536);     // 64 KiB
  float* rb = (float*)(aux + 16384 + 131072);     // 32 KiB
  float* S0w = (float*)(aux + 16384 + 131072 + 32768);
  float* T0d = (float*)(aux + 16384 + 131072 + 32768 + 128);
  f32x2* tst = (f32x2*)(aux + 16384 + 131072 + 32768 + 256);  // 32 KiB
  float* E0 = (float*)(aux + 16384 + 131072 + 32768 + 256 + 32768);  // 32 KiB
  float* E1 = E0 + LL * DD;                                          // 32 KiB
  // Wt lives in d_out: recomputed every call, overwritten by depth_last
  short* Wt = (short*)d_out;

  dim3 tb(256);
  prep_pack<<<32, tb, 0, stream>>>(W_m, W_r, W_b, dyn_gamma, norm_gamma,
                                   norm_beta, gwm, gwr, gwb, rb);
  prep_sums<<<4, dim3(64), 0, stream>>>(W_m, W_r, W_b, dyn_gamma, S0w, T0d);
  transpose_wblk<<<dim3(32, 32, 4), tb, 0, stream>>>(Wblk, norm_gamma, Wt);
  row_sums<<<dim3(512, 4), tb, 0, stream>>>(Wt, rb, bblk, E0, E1);
  width0_kernel<<<1024, tb, 0, stream>>>(x, Hst, hbuf, tst, A_m, A_r, gwm,
                                         gwr, s_a, S0w);
  for (int i = 0; i < LL; i++) {
    gemm_kernel<<<dim3(32, 16), tb, 0, stream>>>(
        hbuf, Wt + (size_t)i * DD * DD, tst, E0 + i * DD, E1 + i * DD, h2);
    if (i < LL - 1)
      fused_dw<<<1024, tb, 0, stream>>>(h2, Hst, hbuf, tst, Bp, gwb, s_b, A_m,
                                        A_r, gwm, gwr, s_a, S0w, T0d, i);
    else
      depth_last<<<1024, tb, 0, stream>>>(h2, Hst, out, Bp, gwb, s_b, T0d, i);
  }
}